// Round 5
// baseline (840.222 us; speedup 1.0000x reference)
//
#include <hip/hip_runtime.h>
#include <math.h>

#define BB 2
#define NN 40960
#define KK 16

typedef float v2f __attribute__((ext_vector_type(2)));
__device__ __forceinline__ v2f fma2(v2f a, v2f b, v2f c){
  return __builtin_elementwise_fma(a, b, c);
}
__device__ __forceinline__ v2f mk2(float a, float b){ v2f r; r.x=a; r.y=b; return r; }

// ---- 16-lane sum on the VALU pipe via DPP ----
template<int CTRL>
__device__ __forceinline__ float dppf(float x){
  return __int_as_float(__builtin_amdgcn_update_dpp(0, __float_as_int(x), CTRL, 0xF, 0xF, true));
}
__device__ __forceinline__ float red16_sum(float v){
  v += dppf<0xB1>(v);    // quad_perm:[1,0,3,2]  (xor 1)
  v += dppf<0x4E>(v);    // quad_perm:[2,3,0,1]  (xor 2)
  v += dppf<0x141>(v);   // row_half_mirror      (xor 4 equiv)
  v += dppf<0x140>(v);   // row_mirror           (xor 8 equiv)
  return v;
}

// ---- BN-folded weights, computed once (30.6 KB) ----
__device__ alignas(16) float g_pw1[32*10];
__device__ alignas(16) float g_pb1[32];
__device__ alignas(16) float g_pw2[32*32];
__device__ alignas(16) float g_pb2[32];
__device__ alignas(16) float g_pcw[32*64];   // ap1 mlp folded
__device__ alignas(16) float g_pcb[32];
__device__ alignas(16) float g_pdw[64*64];   // ap2 mlp folded
__device__ alignas(16) float g_pdb[64];

// Fused: feature transpose (blocks 0..319) + BN-fold prep (last block)
__global__ __launch_bounds__(256) void k_pre(
  const float* __restrict__ feat, float* __restrict__ feat_t,
  const float* __restrict__ w1, const float* __restrict__ b1,
  const float* __restrict__ g1, const float* __restrict__ be1, const float* __restrict__ m1, const float* __restrict__ v1,
  const float* __restrict__ w2, const float* __restrict__ b2,
  const float* __restrict__ g2, const float* __restrict__ be2, const float* __restrict__ m2, const float* __restrict__ v2,
  const float* __restrict__ cw, const float* __restrict__ cb,
  const float* __restrict__ cg, const float* __restrict__ cbe, const float* __restrict__ cm, const float* __restrict__ cv,
  const float* __restrict__ dw, const float* __restrict__ db,
  const float* __restrict__ dg, const float* __restrict__ dbe, const float* __restrict__ dm, const float* __restrict__ dv)
{
  int tid = threadIdx.x;
  int bid = blockIdx.x;
  if (bid < BB*NN/256){
    int b = bid / (NN/256);
    int n = (bid % (NN/256))*256 + tid;
    float v[32];
    #pragma unroll
    for (int h=0; h<32; ++h) v[h] = feat[((size_t)(b*32+h))*NN + n];
    float* o = feat_t + ((size_t)b*NN + n)*32;
    #pragma unroll
    for (int h=0; h<32; h+=4){ *(float4*)(o+h) = make_float4(v[h],v[h+1],v[h+2],v[h+3]); }
    return;
  }
  for (int i=tid; i<320; i+=256){ int h=i/10;
    g_pw1[i] = w1[i] * (g1[h]*rsqrtf(v1[h]+1e-5f)); }
  if (tid<32){ float s=g1[tid]*rsqrtf(v1[tid]+1e-5f);
    g_pb1[tid] = (b1[tid]-m1[tid])*s + be1[tid]; }
  for (int i=tid; i<1024; i+=256){ int h=i>>5;
    g_pw2[i] = w2[i] * (g2[h]*rsqrtf(v2[h]+1e-5f)); }
  if (tid<32){ float s=g2[tid]*rsqrtf(v2[tid]+1e-5f);
    g_pb2[tid] = (b2[tid]-m2[tid])*s + be2[tid]; }
  for (int i=tid; i<2048; i+=256){ int h=i>>6;
    g_pcw[i] = cw[i] * (cg[h]*rsqrtf(cv[h]+1e-5f)); }
  if (tid<32){ float s=cg[tid]*rsqrtf(cv[tid]+1e-5f);
    g_pcb[tid] = (cb[tid]-cm[tid])*s + cbe[tid]; }
  for (int i=tid; i<4096; i+=256){ int h=i>>6;
    g_pdw[i] = dw[i] * (dg[h]*rsqrtf(dv[h]+1e-5f)); }
  if (tid<64){ float s=dg[tid]*rsqrtf(dv[tid]+1e-5f);
    g_pdb[tid] = (db[tid]-dm[tid])*s + dbe[tid]; }
}

// Dual-point: each thread handles points n0 (A) and n0+4 (B), sharing one
// uniform weight stream (s_load) across two independent FMA/DPP chains.
__global__ __launch_bounds__(256,3) void k_stage1(
  const float* __restrict__ xyz, const float* __restrict__ feat_t, const int* __restrict__ nidx,
  const float* __restrict__ fcw, const float* __restrict__ fcb,
  float* __restrict__ fagg)
{
  int tid = threadIdx.x;
  int lane = tid & 63, wvv = tid >> 6;
  int k = lane & 15, ns = lane >> 4;
  int b = blockIdx.x / (NN/32);
  int n0 = (blockIdx.x % (NN/32))*32 + wvv*8 + ns;
  size_t bn0 = (size_t)b*NN + n0;
  size_t bn1 = bn0 + 4;
  int i0 = nidx[bn0*KK + k];
  int i1 = nidx[bn1*KK + k];

  // gathers first; latency hides under enc+mlp1
  alignas(16) float fA[64];
  alignas(16) float fB[64];
  {
    const float* fb0 = feat_t + ((size_t)b*NN + i0)*32;
    const float* fb1 = feat_t + ((size_t)b*NN + i1)*32;
    #pragma unroll
    for (int h=0; h<32; h+=4){
      float4 xa = *(const float4*)(fb0+h);
      float4 xb = *(const float4*)(fb1+h);
      fA[h]=xa.x; fA[h+1]=xa.y; fA[h+2]=xa.z; fA[h+3]=xa.w;
      fB[h]=xb.x; fB[h+1]=xb.y; fB[h+2]=xb.z; fB[h+3]=xb.w;
    }
  }
  v2f eA[5], eB[5];
  {
    const float* tp = xyz + bn0*3; const float* qp = xyz + ((size_t)b*NN + i0)*3;
    float t0=tp[0],t1=tp[1],t2=tp[2], q0=qp[0],q1=qp[1],q2=qp[2];
    float r0=t0-q0,r1=t1-q1,r2=t2-q2;
    eA[0]=mk2(sqrtf(r0*r0+r1*r1+r2*r2),r0); eA[1]=mk2(r1,r2);
    eA[2]=mk2(t0,t1); eA[3]=mk2(t2,q0); eA[4]=mk2(q1,q2);
  }
  {
    const float* tp = xyz + bn1*3; const float* qp = xyz + ((size_t)b*NN + i1)*3;
    float t0=tp[0],t1=tp[1],t2=tp[2], q0=qp[0],q1=qp[1],q2=qp[2];
    float r0=t0-q0,r1=t1-q1,r2=t2-q2;
    eB[0]=mk2(sqrtf(r0*r0+r1*r1+r2*r2),r0); eB[1]=mk2(r1,r2);
    eB[2]=mk2(t0,t1); eB[3]=mk2(t2,q0); eB[4]=mk2(q1,q2);
  }
  // mlp1 (10->32, BN pre-folded, relu) — one weight stream, two chains
  #pragma unroll
  for (int h=0; h<32; ++h){
    const v2f* wr = (const v2f*)(g_pw1 + h*10);
    v2f aA = mk2(g_pb1[h],0.f), aB = mk2(g_pb1[h],0.f);
    #pragma unroll
    for (int c=0; c<5; ++c){ aA = fma2(wr[c], eA[c], aA); aB = fma2(wr[c], eB[c], aB); }
    fA[32+h] = fmaxf(aA.x+aA.y, 0.f);
    fB[32+h] = fmaxf(aB.x+aB.y, 0.f);
  }
  // fc1 + relu + softmax over K + weighted agg — 2 points x channel-pairs
  const v2f* fvA = (const v2f*)fA;
  const v2f* fvB = (const v2f*)fB;
  float spA[4], sfA[4], spB[4], sfB[4];
  #pragma unroll
  for (int ob=0; ob<64; ob+=2){
    const v2f* w0 = (const v2f*)(fcw + ob*64);
    const v2f* w1p = (const v2f*)(fcw + (ob+1)*64);
    v2f aA0 = mk2(fcb[ob],0.f), aA1 = mk2(fcb[ob+1],0.f);
    v2f aB0 = mk2(fcb[ob],0.f), aB1 = mk2(fcb[ob+1],0.f);
    #pragma unroll
    for (int c=0; c<32; ++c){
      aA0 = fma2(w0[c], fvA[c], aA0); aA1 = fma2(w1p[c], fvA[c], aA1);
      aB0 = fma2(w0[c], fvB[c], aB0); aB1 = fma2(w1p[c], fvB[c], aB1);
    }
    float lA0 = fmaxf(aA0.x+aA0.y,0.f), lA1 = fmaxf(aA1.x+aA1.y,0.f);
    float lB0 = fmaxf(aB0.x+aB0.y,0.f), lB1 = fmaxf(aB1.x+aB1.y,0.f);
    float pA0 = __expf(lA0), pA1 = __expf(lA1);
    float pB0 = __expf(lB0), pB1 = __expf(lB1);
    float gA0 = fA[ob]*pA0, gA1 = fA[ob+1]*pA1;
    float gB0 = fB[ob]*pB0, gB1 = fB[ob+1]*pB1;
    float sA0 = red16_sum(pA0), tA0 = red16_sum(gA0);
    float sA1 = red16_sum(pA1), tA1 = red16_sum(gA1);
    float sB0 = red16_sum(pB0), tB0 = red16_sum(gB0);
    float sB1 = red16_sum(pB1), tB1 = red16_sum(gB1);
    if ((ob>>2)==k){
      spA[ob&3]=sA0; sfA[ob&3]=tA0; spA[(ob+1)&3]=sA1; sfA[(ob+1)&3]=tA1;
      spB[ob&3]=sB0; sfB[ob&3]=tB0; spB[(ob+1)&3]=sB1; sfB[(ob+1)&3]=tB1;
    }
  }
  v2f a01A = mk2(__fdividef(sfA[0],spA[0]), __fdividef(sfA[1],spA[1]));
  v2f a23A = mk2(__fdividef(sfA[2],spA[2]), __fdividef(sfA[3],spA[3]));
  v2f a01B = mk2(__fdividef(sfB[0],spB[0]), __fdividef(sfB[1],spB[1]));
  v2f a23B = mk2(__fdividef(sfB[2],spB[2]), __fdividef(sfB[3],spB[3]));

  // ap1 mlp (64->32, BN pre-folded, relu)
  float o0A=0.f,o1A=0.f,o0B=0.f,o1B=0.f;
  #pragma unroll
  for (int h=0; h<32; ++h){
    const v2f* wr = (const v2f*)(g_pcw + h*64 + 4*k);
    v2f pA = fma2(wr[0], a01A, wr[1]*a23A);
    v2f pB = fma2(wr[0], a01B, wr[1]*a23B);
    float rA = red16_sum(pA.x + pA.y);
    float rB = red16_sum(pB.x + pB.y);
    float vA = fmaxf(rA + g_pcb[h], 0.f);
    float vB = fmaxf(rB + g_pcb[h], 0.f);
    if ((h&15)==k){ if (h<16){ o0A=vA; o0B=vB; } else { o1A=vA; o1B=vB; } }
  }
  float* f0 = fagg + bn0*32;
  float* f1 = fagg + bn1*32;
  f0[k]=o0A; f0[k+16]=o1A;
  f1[k]=o0B; f1[k+16]=o1B;
}

__global__ __launch_bounds__(256,3) void k_stage2(
  const float* __restrict__ xyz, const float* __restrict__ fagg, const int* __restrict__ nidx,
  const float* __restrict__ fcw, const float* __restrict__ fcb,
  float* __restrict__ outp)
{
  int tid = threadIdx.x;
  int lane = tid & 63, wvv = tid >> 6;
  int k = lane & 15, ns = lane >> 4;
  int b = blockIdx.x / (NN/32);
  int n0 = (blockIdx.x % (NN/32))*32 + wvv*8 + ns;
  size_t bn0 = (size_t)b*NN + n0;
  size_t bn1 = bn0 + 4;
  int i0 = nidx[bn0*KK + k];
  int i1 = nidx[bn1*KK + k];

  v2f eA[5], eB[5];
  {
    const float* tp = xyz + bn0*3; const float* qp = xyz + ((size_t)b*NN + i0)*3;
    float t0=tp[0],t1=tp[1],t2=tp[2], q0=qp[0],q1=qp[1],q2=qp[2];
    float r0=t0-q0,r1=t1-q1,r2=t2-q2;
    eA[0]=mk2(sqrtf(r0*r0+r1*r1+r2*r2),r0); eA[1]=mk2(r1,r2);
    eA[2]=mk2(t0,t1); eA[3]=mk2(t2,q0); eA[4]=mk2(q1,q2);
  }
  {
    const float* tp = xyz + bn1*3; const float* qp = xyz + ((size_t)b*NN + i1)*3;
    float t0=tp[0],t1=tp[1],t2=tp[2], q0=qp[0],q1=qp[1],q2=qp[2];
    float r0=t0-q0,r1=t1-q1,r2=t2-q2;
    eB[0]=mk2(sqrtf(r0*r0+r1*r1+r2*r2),r0); eB[1]=mk2(r1,r2);
    eB[2]=mk2(t0,t1); eB[3]=mk2(t2,q0); eB[4]=mk2(q1,q2);
  }
  // mlp1 (recompute f_xyz)
  alignas(8) float fxA[32];
  alignas(8) float fxB[32];
  #pragma unroll
  for (int h=0; h<32; ++h){
    const v2f* wr = (const v2f*)(g_pw1 + h*10);
    v2f aA = mk2(g_pb1[h],0.f), aB = mk2(g_pb1[h],0.f);
    #pragma unroll
    for (int c=0; c<5; ++c){ aA = fma2(wr[c], eA[c], aA); aB = fma2(wr[c], eB[c], aB); }
    fxA[h] = fmaxf(aA.x+aA.y, 0.f);
    fxB[h] = fmaxf(aB.x+aB.y, 0.f);
  }
  // mlp2 (32->32)
  alignas(16) float fA[64];
  alignas(16) float fB[64];
  const v2f* fxvA = (const v2f*)fxA;
  const v2f* fxvB = (const v2f*)fxB;
  #pragma unroll
  for (int h=0; h<32; ++h){
    const v2f* wr = (const v2f*)(g_pw2 + h*32);
    v2f aA = mk2(g_pb2[h],0.f), aB = mk2(g_pb2[h],0.f);
    #pragma unroll
    for (int c=0; c<16; ++c){ aA = fma2(wr[c], fxvA[c], aA); aB = fma2(wr[c], fxvB[c], aB); }
    fA[32+h] = fmaxf(aA.x+aA.y, 0.f);
    fB[32+h] = fmaxf(aB.x+aB.y, 0.f);
  }
  // gather f_agg neighbor rows AFTER mlp2 (keeps VGPR peak down; fx dies here)
  {
    const float* fb0 = fagg + ((size_t)b*NN + i0)*32;
    const float* fb1 = fagg + ((size_t)b*NN + i1)*32;
    #pragma unroll
    for (int h=0; h<32; h+=4){
      float4 xa = *(const float4*)(fb0+h);
      float4 xb = *(const float4*)(fb1+h);
      fA[h]=xa.x; fA[h+1]=xa.y; fA[h+2]=xa.z; fA[h+3]=xa.w;
      fB[h]=xb.x; fB[h+1]=xb.y; fB[h+2]=xb.z; fB[h+3]=xb.w;
    }
  }
  // fc2 + relu + softmax over K + weighted agg
  const v2f* fvA = (const v2f*)fA;
  const v2f* fvB = (const v2f*)fB;
  float spA[4], sfA[4], spB[4], sfB[4];
  #pragma unroll
  for (int ob=0; ob<64; ob+=2){
    const v2f* w0 = (const v2f*)(fcw + ob*64);
    const v2f* w1p = (const v2f*)(fcw + (ob+1)*64);
    v2f aA0 = mk2(fcb[ob],0.f), aA1 = mk2(fcb[ob+1],0.f);
    v2f aB0 = mk2(fcb[ob],0.f), aB1 = mk2(fcb[ob+1],0.f);
    #pragma unroll
    for (int c=0; c<32; ++c){
      aA0 = fma2(w0[c], fvA[c], aA0); aA1 = fma2(w1p[c], fvA[c], aA1);
      aB0 = fma2(w0[c], fvB[c], aB0); aB1 = fma2(w1p[c], fvB[c], aB1);
    }
    float lA0 = fmaxf(aA0.x+aA0.y,0.f), lA1 = fmaxf(aA1.x+aA1.y,0.f);
    float lB0 = fmaxf(aB0.x+aB0.y,0.f), lB1 = fmaxf(aB1.x+aB1.y,0.f);
    float pA0 = __expf(lA0), pA1 = __expf(lA1);
    float pB0 = __expf(lB0), pB1 = __expf(lB1);
    float gA0 = fA[ob]*pA0, gA1 = fA[ob+1]*pA1;
    float gB0 = fB[ob]*pB0, gB1 = fB[ob+1]*pB1;
    float sA0 = red16_sum(pA0), tA0 = red16_sum(gA0);
    float sA1 = red16_sum(pA1), tA1 = red16_sum(gA1);
    float sB0 = red16_sum(pB0), tB0 = red16_sum(gB0);
    float sB1 = red16_sum(pB1), tB1 = red16_sum(gB1);
    if ((ob>>2)==k){
      spA[ob&3]=sA0; sfA[ob&3]=tA0; spA[(ob+1)&3]=sA1; sfA[(ob+1)&3]=tA1;
      spB[ob&3]=sB0; sfB[ob&3]=tB0; spB[(ob+1)&3]=sB1; sfB[(ob+1)&3]=tB1;
    }
  }
  v2f a01A = mk2(__fdividef(sfA[0],spA[0]), __fdividef(sfA[1],spA[1]));
  v2f a23A = mk2(__fdividef(sfA[2],spA[2]), __fdividef(sfA[3],spA[3]));
  v2f a01B = mk2(__fdividef(sfB[0],spB[0]), __fdividef(sfB[1],spB[1]));
  v2f a23B = mk2(__fdividef(sfB[2],spB[2]), __fdividef(sfB[3],spB[3]));

  // ap2 mlp (64->64, BN pre-folded, relu) -> output
  float oA[4], oB[4];
  #pragma unroll
  for (int h=0; h<64; ++h){
    const v2f* wr = (const v2f*)(g_pdw + h*64 + 4*k);
    v2f pA = fma2(wr[0], a01A, wr[1]*a23A);
    v2f pB = fma2(wr[0], a01B, wr[1]*a23B);
    float rA = red16_sum(pA.x + pA.y);
    float rB = red16_sum(pB.x + pB.y);
    float vA = fmaxf(rA + g_pdb[h], 0.f);
    float vB = fmaxf(rB + g_pdb[h], 0.f);
    if ((h&15)==k){ oA[h>>4]=vA; oB[h>>4]=vB; }
  }
  #pragma unroll
  for (int j=0; j<4; ++j){
    outp[((size_t)(b*64 + k + 16*j))*NN + n0] = oA[j];
    outp[((size_t)(b*64 + k + 16*j))*NN + n0 + 4] = oB[j];
  }
}

extern "C" void kernel_launch(void* const* d_in, const int* in_sizes, int n_in,
                              void* d_out, int out_size, void* d_ws, size_t ws_size,
                              hipStream_t stream){
  const float* xyz     = (const float*)d_in[0];
  const float* feature = (const float*)d_in[1];
  const int*   nidx    = (const int*)d_in[30];
  float* feat_t = (float*)d_ws;                       // (B,N,32)
  float* fagg   = feat_t + (size_t)BB*NN*32;          // (B,N,32)

  k_pre<<<BB*NN/256 + 1, 256, 0, stream>>>(feature, feat_t,
    (const float*)d_in[2],(const float*)d_in[3],(const float*)d_in[4],(const float*)d_in[5],
    (const float*)d_in[6],(const float*)d_in[7],
    (const float*)d_in[16],(const float*)d_in[17],(const float*)d_in[18],(const float*)d_in[19],
    (const float*)d_in[20],(const float*)d_in[21],
    (const float*)d_in[10],(const float*)d_in[11],(const float*)d_in[12],(const float*)d_in[13],
    (const float*)d_in[14],(const float*)d_in[15],
    (const float*)d_in[24],(const float*)d_in[25],(const float*)d_in[26],(const float*)d_in[27],
    (const float*)d_in[28],(const float*)d_in[29]);
  k_stage1<<<BB*NN/32, 256, 0, stream>>>(xyz, feat_t, nidx,
    (const float*)d_in[8],(const float*)d_in[9], fagg);
  k_stage2<<<BB*NN/32, 256, 0, stream>>>(xyz, fagg, nidx,
    (const float*)d_in[22],(const float*)d_in[23], (float*)d_out);
}

// Round 6
// 436.686 us; speedup vs baseline: 1.9241x; 1.9241x over previous
//
#include <hip/hip_runtime.h>
#include <math.h>

#define BB 2
#define NN 40960
#define KK 16

typedef float v2f __attribute__((ext_vector_type(2)));
__device__ __forceinline__ v2f fma2(v2f a, v2f b, v2f c){
  return __builtin_elementwise_fma(a, b, c);
}
__device__ __forceinline__ v2f mk2(float a, float b){ v2f r; r.x=a; r.y=b; return r; }

// ---- 16-lane sum on the VALU pipe via DPP ----
template<int CTRL>
__device__ __forceinline__ float dppf(float x){
  return __int_as_float(__builtin_amdgcn_update_dpp(0, __float_as_int(x), CTRL, 0xF, 0xF, true));
}
__device__ __forceinline__ float red16_sum(float v){
  v += dppf<0xB1>(v);    // quad_perm:[1,0,3,2]  (xor 1)
  v += dppf<0x4E>(v);    // quad_perm:[2,3,0,1]  (xor 2)
  v += dppf<0x141>(v);   // row_half_mirror      (xor 4 equiv)
  v += dppf<0x140>(v);   // row_mirror           (xor 8 equiv)
  return v;
}

// ---- BN-folded weights, computed once (30.6 KB) ----
__device__ alignas(16) float g_pw1[32*10];
__device__ alignas(16) float g_pb1[32];
__device__ alignas(16) float g_pw2[32*32];
__device__ alignas(16) float g_pb2[32];
__device__ alignas(16) float g_pcw[32*64];   // ap1 mlp folded
__device__ alignas(16) float g_pcb[32];
__device__ alignas(16) float g_pdw[64*64];   // ap2 mlp folded
__device__ alignas(16) float g_pdb[64];

// Fused: feature transpose (blocks 0..319) + BN-fold prep (last block)
__global__ __launch_bounds__(256) void k_pre(
  const float* __restrict__ feat, float* __restrict__ feat_t,
  const float* __restrict__ w1, const float* __restrict__ b1,
  const float* __restrict__ g1, const float* __restrict__ be1, const float* __restrict__ m1, const float* __restrict__ v1,
  const float* __restrict__ w2, const float* __restrict__ b2,
  const float* __restrict__ g2, const float* __restrict__ be2, const float* __restrict__ m2, const float* __restrict__ v2,
  const float* __restrict__ cw, const float* __restrict__ cb,
  const float* __restrict__ cg, const float* __restrict__ cbe, const float* __restrict__ cm, const float* __restrict__ cv,
  const float* __restrict__ dw, const float* __restrict__ db,
  const float* __restrict__ dg, const float* __restrict__ dbe, const float* __restrict__ dm, const float* __restrict__ dv)
{
  int tid = threadIdx.x;
  int bid = blockIdx.x;
  if (bid < BB*NN/256){
    int b = bid / (NN/256);
    int n = (bid % (NN/256))*256 + tid;
    float v[32];
    #pragma unroll
    for (int h=0; h<32; ++h) v[h] = feat[((size_t)(b*32+h))*NN + n];
    float* o = feat_t + ((size_t)b*NN + n)*32;
    #pragma unroll
    for (int h=0; h<32; h+=4){ *(float4*)(o+h) = make_float4(v[h],v[h+1],v[h+2],v[h+3]); }
    return;
  }
  for (int i=tid; i<320; i+=256){ int h=i/10;
    g_pw1[i] = w1[i] * (g1[h]*rsqrtf(v1[h]+1e-5f)); }
  if (tid<32){ float s=g1[tid]*rsqrtf(v1[tid]+1e-5f);
    g_pb1[tid] = (b1[tid]-m1[tid])*s + be1[tid]; }
  for (int i=tid; i<1024; i+=256){ int h=i>>5;
    g_pw2[i] = w2[i] * (g2[h]*rsqrtf(v2[h]+1e-5f)); }
  if (tid<32){ float s=g2[tid]*rsqrtf(v2[tid]+1e-5f);
    g_pb2[tid] = (b2[tid]-m2[tid])*s + be2[tid]; }
  for (int i=tid; i<2048; i+=256){ int h=i>>6;
    g_pcw[i] = cw[i] * (cg[h]*rsqrtf(cv[h]+1e-5f)); }
  if (tid<32){ float s=cg[tid]*rsqrtf(cv[tid]+1e-5f);
    g_pcb[tid] = (cb[tid]-cm[tid])*s + cbe[tid]; }
  for (int i=tid; i<4096; i+=256){ int h=i>>6;
    g_pdw[i] = dw[i] * (dg[h]*rsqrtf(dv[h]+1e-5f)); }
  if (tid<64){ float s=dg[tid]*rsqrtf(dv[tid]+1e-5f);
    g_pdb[tid] = (db[tid]-dm[tid])*s + dbe[tid]; }
}

__global__ __launch_bounds__(256,2) void k_stage1(
  const float* __restrict__ xyz, const float* __restrict__ feat_t, const int* __restrict__ nidx,
  const float* __restrict__ fcw, const float* __restrict__ fcb,
  float* __restrict__ fagg)
{
  int tid = threadIdx.x;
  int lane = tid & 63, wvv = tid >> 6;
  int k = lane & 15, ns = lane >> 4;
  int b = blockIdx.x / (NN/16);
  int n = (blockIdx.x % (NN/16))*16 + wvv*4 + ns;
  size_t bn = (size_t)b*NN + n;
  int idxv = nidx[bn*KK + k];

  // scattered gathers first; latency hides under mlp1
  alignas(16) float fc_[64];
  const float* fb = feat_t + ((size_t)b*NN + idxv)*32;
  #pragma unroll
  for (int h=0; h<32; h+=4){ float4 x=*(const float4*)(fb+h);
    fc_[h]=x.x; fc_[h+1]=x.y; fc_[h+2]=x.z; fc_[h+3]=x.w; }

  const float* tp = xyz + bn*3;
  const float* qp = xyz + ((size_t)b*NN + idxv)*3;
  float t0=tp[0],t1=tp[1],t2=tp[2];
  float q0=qp[0],q1=qp[1],q2=qp[2];
  float r0=t0-q0,r1=t1-q1,r2=t2-q2;
  v2f e2[5] = { {sqrtf(r0*r0+r1*r1+r2*r2), r0}, {r1,r2}, {t0,t1}, {t2,q0}, {q1,q2} };

  // mlp1 (10->32, BN pre-folded, relu)
  #pragma unroll
  for (int h=0; h<32; ++h){
    const v2f* wr = (const v2f*)(g_pw1 + h*10);
    v2f acc = mk2(g_pb1[h], 0.f);
    #pragma unroll
    for (int c=0; c<5; ++c) acc = fma2(wr[c], e2[c], acc);
    fc_[32+h] = fmaxf(acc.x+acc.y, 0.f);
  }

  // fc1 (64->64) + relu + softmax over K + weighted agg — channel QUADS:
  // all 4 channels of a quad belong to the same owner lane (ob>>2 const).
  const v2f* fv = (const v2f*)fc_;
  float sp4[4], sf4[4];
  #pragma unroll
  for (int ob=0; ob<64; ob+=4){
    const v2f* w0 = (const v2f*)(fcw + ob*64);
    const v2f* w1p = (const v2f*)(fcw + (ob+1)*64);
    const v2f* w2p = (const v2f*)(fcw + (ob+2)*64);
    const v2f* w3p = (const v2f*)(fcw + (ob+3)*64);
    v2f a0=mk2(fcb[ob],0.f), a1=mk2(fcb[ob+1],0.f), a2=mk2(fcb[ob+2],0.f), a3=mk2(fcb[ob+3],0.f);
    #pragma unroll
    for (int c=0; c<32; ++c){
      v2f f = fv[c];
      a0 = fma2(w0[c], f, a0); a1 = fma2(w1p[c], f, a1);
      a2 = fma2(w2p[c], f, a2); a3 = fma2(w3p[c], f, a3);
    }
    float l0=fmaxf(a0.x+a0.y,0.f), l1=fmaxf(a1.x+a1.y,0.f);
    float l2=fmaxf(a2.x+a2.y,0.f), l3=fmaxf(a3.x+a3.y,0.f);
    float p0=__expf(l0), p1=__expf(l1), p2=__expf(l2), p3=__expf(l3);
    float q0v=fc_[ob]*p0, q1v=fc_[ob+1]*p1, q2v=fc_[ob+2]*p2, q3v=fc_[ob+3]*p3;
    float s0=red16_sum(p0), s1=red16_sum(p1), s2=red16_sum(p2), s3=red16_sum(p3);
    float t0v=red16_sum(q0v), t1v=red16_sum(q1v), t2v=red16_sum(q2v), t3v=red16_sum(q3v);
    if ((ob>>2)==k){
      sp4[0]=s0; sp4[1]=s1; sp4[2]=s2; sp4[3]=s3;
      sf4[0]=t0v; sf4[1]=t1v; sf4[2]=t2v; sf4[3]=t3v;
    }
  }
  v2f a01 = mk2(__fdividef(sf4[0],sp4[0]), __fdividef(sf4[1],sp4[1]));
  v2f a23 = mk2(__fdividef(sf4[2],sp4[2]), __fdividef(sf4[3],sp4[3]));

  // ap1 mlp (64->32, BN pre-folded, relu) — h pairs for ILP
  float o0=0.f, o1=0.f;
  #pragma unroll
  for (int h=0; h<32; h+=2){
    const v2f* wr0 = (const v2f*)(g_pcw + h*64 + 4*k);
    const v2f* wr1 = (const v2f*)(g_pcw + (h+1)*64 + 4*k);
    v2f p0 = fma2(wr0[0], a01, wr0[1]*a23);
    v2f p1 = fma2(wr1[0], a01, wr1[1]*a23);
    float r0v = red16_sum(p0.x + p0.y);
    float r1v = red16_sum(p1.x + p1.y);
    float v0 = fmaxf(r0v + g_pcb[h], 0.f);
    float v1 = fmaxf(r1v + g_pcb[h+1], 0.f);
    if ((h&15)==k){ if (h<16) o0=v0; else o1=v0; }
    if (((h+1)&15)==k){ if (h+1<16) o0=v1; else o1=v1; }
  }
  float* fo = fagg + bn*32;
  fo[k]=o0; fo[k+16]=o1;
}

__global__ __launch_bounds__(256,2) void k_stage2(
  const float* __restrict__ xyz, const float* __restrict__ fagg, const int* __restrict__ nidx,
  const float* __restrict__ fcw, const float* __restrict__ fcb,
  float* __restrict__ outp)
{
  int tid = threadIdx.x;
  int lane = tid & 63, wvv = tid >> 6;
  int k = lane & 15, ns = lane >> 4;
  int b = blockIdx.x / (NN/16);
  int n = (blockIdx.x % (NN/16))*16 + wvv*4 + ns;
  size_t bn = (size_t)b*NN + n;
  int idxv = nidx[bn*KK + k];

  // scattered gather first; latency hides under mlp1+mlp2
  alignas(16) float fc_[64];
  const float* fb = fagg + ((size_t)b*NN + idxv)*32;
  #pragma unroll
  for (int h=0; h<32; h+=4){ float4 x=*(const float4*)(fb+h);
    fc_[h]=x.x; fc_[h+1]=x.y; fc_[h+2]=x.z; fc_[h+3]=x.w; }

  const float* tp = xyz + bn*3;
  const float* qp = xyz + ((size_t)b*NN + idxv)*3;
  float t0=tp[0],t1=tp[1],t2=tp[2];
  float q0=qp[0],q1=qp[1],q2=qp[2];
  float r0=t0-q0,r1=t1-q1,r2=t2-q2;
  v2f e2[5] = { {sqrtf(r0*r0+r1*r1+r2*r2), r0}, {r1,r2}, {t0,t1}, {t2,q0}, {q1,q2} };

  // recompute f_xyz (mlp1)
  alignas(8) float fx[32];
  #pragma unroll
  for (int h=0; h<32; ++h){
    const v2f* wr = (const v2f*)(g_pw1 + h*10);
    v2f acc = mk2(g_pb1[h], 0.f);
    #pragma unroll
    for (int c=0; c<5; ++c) acc = fma2(wr[c], e2[c], acc);
    fx[h] = fmaxf(acc.x+acc.y, 0.f);
  }

  // mlp2 (32->32, BN pre-folded, relu)
  const v2f* fxv = (const v2f*)fx;
  #pragma unroll
  for (int h=0; h<32; ++h){
    const v2f* wr = (const v2f*)(g_pw2 + h*32);
    v2f acc = mk2(g_pb2[h], 0.f);
    #pragma unroll
    for (int c=0; c<16; ++c) acc = fma2(wr[c], fxv[c], acc);
    fc_[32+h] = fmaxf(acc.x+acc.y, 0.f);
  }

  // fc2 + relu + softmax over K + weighted agg — channel quads
  const v2f* fv = (const v2f*)fc_;
  float sp4[4], sf4[4];
  #pragma unroll
  for (int ob=0; ob<64; ob+=4){
    const v2f* w0 = (const v2f*)(fcw + ob*64);
    const v2f* w1p = (const v2f*)(fcw + (ob+1)*64);
    const v2f* w2p = (const v2f*)(fcw + (ob+2)*64);
    const v2f* w3p = (const v2f*)(fcw + (ob+3)*64);
    v2f a0=mk2(fcb[ob],0.f), a1=mk2(fcb[ob+1],0.f), a2=mk2(fcb[ob+2],0.f), a3=mk2(fcb[ob+3],0.f);
    #pragma unroll
    for (int c=0; c<32; ++c){
      v2f f = fv[c];
      a0 = fma2(w0[c], f, a0); a1 = fma2(w1p[c], f, a1);
      a2 = fma2(w2p[c], f, a2); a3 = fma2(w3p[c], f, a3);
    }
    float l0=fmaxf(a0.x+a0.y,0.f), l1=fmaxf(a1.x+a1.y,0.f);
    float l2=fmaxf(a2.x+a2.y,0.f), l3=fmaxf(a3.x+a3.y,0.f);
    float p0=__expf(l0), p1=__expf(l1), p2=__expf(l2), p3=__expf(l3);
    float q0v=fc_[ob]*p0, q1v=fc_[ob+1]*p1, q2v=fc_[ob+2]*p2, q3v=fc_[ob+3]*p3;
    float s0=red16_sum(p0), s1=red16_sum(p1), s2=red16_sum(p2), s3=red16_sum(p3);
    float t0v=red16_sum(q0v), t1v=red16_sum(q1v), t2v=red16_sum(q2v), t3v=red16_sum(q3v);
    if ((ob>>2)==k){
      sp4[0]=s0; sp4[1]=s1; sp4[2]=s2; sp4[3]=s3;
      sf4[0]=t0v; sf4[1]=t1v; sf4[2]=t2v; sf4[3]=t3v;
    }
  }
  v2f a01 = mk2(__fdividef(sf4[0],sp4[0]), __fdividef(sf4[1],sp4[1]));
  v2f a23 = mk2(__fdividef(sf4[2],sp4[2]), __fdividef(sf4[3],sp4[3]));

  // ap2 mlp (64->64, BN pre-folded, relu) -> output — h pairs for ILP
  float o4[4];
  #pragma unroll
  for (int h=0; h<64; h+=2){
    const v2f* wr0 = (const v2f*)(g_pdw + h*64 + 4*k);
    const v2f* wr1 = (const v2f*)(g_pdw + (h+1)*64 + 4*k);
    v2f p0 = fma2(wr0[0], a01, wr0[1]*a23);
    v2f p1 = fma2(wr1[0], a01, wr1[1]*a23);
    float r0v = red16_sum(p0.x + p0.y);
    float r1v = red16_sum(p1.x + p1.y);
    float v0 = fmaxf(r0v + g_pdb[h], 0.f);
    float v1 = fmaxf(r1v + g_pdb[h+1], 0.f);
    if ((h&15)==k) o4[h>>4] = v0;
    if (((h+1)&15)==k) o4[(h+1)>>4] = v1;
  }
  #pragma unroll
  for (int j=0; j<4; ++j)
    outp[((size_t)(b*64 + k + 16*j))*NN + n] = o4[j];
}

extern "C" void kernel_launch(void* const* d_in, const int* in_sizes, int n_in,
                              void* d_out, int out_size, void* d_ws, size_t ws_size,
                              hipStream_t stream){
  const float* xyz     = (const float*)d_in[0];
  const float* feature = (const float*)d_in[1];
  const int*   nidx    = (const int*)d_in[30];
  float* feat_t = (float*)d_ws;                       // (B,N,32)
  float* fagg   = feat_t + (size_t)BB*NN*32;          // (B,N,32)

  k_pre<<<BB*NN/256 + 1, 256, 0, stream>>>(feature, feat_t,
    (const float*)d_in[2],(const float*)d_in[3],(const float*)d_in[4],(const float*)d_in[5],
    (const float*)d_in[6],(const float*)d_in[7],
    (const float*)d_in[16],(const float*)d_in[17],(const float*)d_in[18],(const float*)d_in[19],
    (const float*)d_in[20],(const float*)d_in[21],
    (const float*)d_in[10],(const float*)d_in[11],(const float*)d_in[12],(const float*)d_in[13],
    (const float*)d_in[14],(const float*)d_in[15],
    (const float*)d_in[24],(const float*)d_in[25],(const float*)d_in[26],(const float*)d_in[27],
    (const float*)d_in[28],(const float*)d_in[29]);
  k_stage1<<<BB*NN/16, 256, 0, stream>>>(xyz, feat_t, nidx,
    (const float*)d_in[8],(const float*)d_in[9], fagg);
  k_stage2<<<BB*NN/16, 256, 0, stream>>>(xyz, fagg, nidx,
    (const float*)d_in[22],(const float*)d_in[23], (float*)d_out);
}